// Round 8
// baseline (633.379 us; speedup 1.0000x reference)
//
#include <hip/hip_runtime.h>

// DynamicRouting: grouped 1x1 conv (G=8, FI=FO=64) + 3-iter sigmoid routing.
// v8: FUSED again, but with the occupancy problem solved.
// Evidence chain:
//  - v5 (fused, con[8][16]=128 f32/thread): 2 waves/SIMD, VALU 24.7%, 305us.
//    Staging/sync variations provably irrelevant (v2==v5 counters).
//  - v6/v7 (split): conv alone hits VALU 38-44% at 28-56 VGPR; but the split
//    mandates 836MB of HBM traffic (con roundtrip) => >=133us floor + 2 ramps.
//  - v7: global->reg x + s_load weights works; L1/L2 dedup redundant per-wave
//    tile reads (FETCH stayed ~132MB at 4x redundancy).
// v8 = fused, 512 thr (8 waves), thread = (px p, fo-eighth q), con[8][8]=64.
//  - x read straight into VGPRs in 16-ch subchunks (coalesced dwords); NO LDS
//    in the conv phase (v5's [ch][px] LDS layout was ds_read_b32-pipe-bound:
//    ~185cyc/wave/chunk vs 256cyc VALU, 1 LDS pipe vs 4 SIMDs).
//  - weights wave-uniform -> s_load; no lgkmcnt/vmcnt cross-serialization.
//  - launch_bounds(512,2): VGPR cap 256 so the compiler CANNOT repeat v4's
//    forced-spill-at-128 (natural pressure ~110 -> 2 WG/CU = 4 waves/SIMD).
//  - one raw s_barrier per group keeps the 8 waves sweeping the same 128KB
//    x-tile in lockstep (L1 reuse). No data dependence on it.
//  - routing: v5 block, 8-partial LDS reduce (20KB). Fallback spill-falsifier:
//    WRITE_SIZE must be exactly 32768 KB.

#define NG 8
#define NFO 64
#define NFI 64
#define NB 32
#define NH 64
#define NW 64
#define HW (NH * NW)   // 4096 pixels per (b, channel) plane

typedef float v2f __attribute__((ext_vector_type(2)));

__global__ __launch_bounds__(512, 2) void dynrout_kernel(
    const float* __restrict__ x, const float* __restrict__ weight,
    const float* __restrict__ bias, float* __restrict__ out)
{
    const int tid = threadIdx.x;
    const int p = tid & 63;
    const int q = __builtin_amdgcn_readfirstlane(tid >> 6);  // fo-eighth, wave-uniform

    const int wg = blockIdx.x;
    const int b = wg >> 6;
    const int h = wg & 63;

    // this thread's pixel column: x[b][ch][h][p], ch stride = HW
    const float* xcol = x + (size_t)b * (NG * NFI) * HW + (size_t)h * NW + p;

    float con[8][8];

    // ---- grouped 1x1 conv: con[g][f] = sum_i w[g][q*8+f][i] * x[g*64+i] ----
#pragma unroll
    for (int g = 0; g < 8; ++g) {
        const float* xg = xcol + (size_t)g * NFI * HW;
        const float* wgb = weight + ((size_t)g * NFO + (size_t)q * 8) * NFI;

        v2f acc[8];
#pragma unroll
        for (int f = 0; f < 8; ++f) acc[f] = (v2f){0.f, 0.f};

#pragma unroll
        for (int sub = 0; sub < 4; ++sub) {          // 16 channels per subchunk
            v2f xr[8];
#pragma unroll
            for (int j = 0; j < 8; ++j) {
                xr[j].x = xg[(size_t)(sub * 16 + 2 * j) * HW];
                xr[j].y = xg[(size_t)(sub * 16 + 2 * j + 1) * HW];
            }
#pragma unroll
            for (int f = 0; f < 8; ++f) {
                const float* wr = wgb + f * NFI + sub * 16;   // wave-uniform -> s_load
#pragma unroll
                for (int j = 0; j < 8; ++j) {
                    const v2f wv = *(const v2f*)(wr + 2 * j);
                    acc[f] = __builtin_elementwise_fma(wv, xr[j], acc[f]);
                }
            }
        }
#pragma unroll
        for (int f = 0; f < 8; ++f) con[g][f] = acc[f].x + acc[f].y;

        // keep the 8 waves sweeping the same x-tile in lockstep (L1 reuse).
        // No data dependence; all 512 threads reach it uniformly.
        __builtin_amdgcn_s_barrier();
    }

    // ---- routing ----
    __shared__ float pbuf[8][8][64];   // per-wave partial beta sums (16 KB)
    __shared__ float alphaS[8][64];
    __shared__ float betaS[8][64];

    float v[8];

    // iter 0: alpha = sigmoid(0) = 0.5; v0 = 0.5 * sum_g con
#pragma unroll
    for (int f = 0; f < 8; ++f) {
        float s = con[0][f];
#pragma unroll
        for (int g = 1; g < 8; ++g) s += con[g][f];
        v[f] = 0.5f * s;
    }
#pragma unroll
    for (int g = 0; g < 8; ++g) {
        float s = 0.f;
#pragma unroll
        for (int f = 0; f < 8; ++f) s = fmaf(v[f], con[g][f], s);
        pbuf[q][g][p] = s;
    }
    __syncthreads();
    {
        const int gg = tid >> 6, pp = tid & 63;   // one (g,px) pair per thread
        float bs = 0.f;
#pragma unroll
        for (int w = 0; w < 8; ++w) bs += pbuf[w][gg][pp];
        betaS[gg][pp] = bs;
        alphaS[gg][pp] = 1.f / (1.f + __expf(-bs));
    }
    __syncthreads();

    // iter 1: v1 = sum_g alpha1*con; beta2 partials
    float a[8];
#pragma unroll
    for (int g = 0; g < 8; ++g) a[g] = alphaS[g][p];
#pragma unroll
    for (int f = 0; f < 8; ++f) {
        float s = 0.f;
#pragma unroll
        for (int g = 0; g < 8; ++g) s = fmaf(a[g], con[g][f], s);
        v[f] = s;
    }
#pragma unroll
    for (int g = 0; g < 8; ++g) {
        float s = 0.f;
#pragma unroll
        for (int f = 0; f < 8; ++f) s = fmaf(v[f], con[g][f], s);
        pbuf[q][g][p] = s;
    }
    __syncthreads();
    {
        const int gg = tid >> 6, pp = tid & 63;
        float bs = betaS[gg][pp];
#pragma unroll
        for (int w = 0; w < 8; ++w) bs += pbuf[w][gg][pp];
        alphaS[gg][pp] = 1.f / (1.f + __expf(-bs));
    }
    __syncthreads();

    // iter 2: out = sum_g alpha2*con + bias
#pragma unroll
    for (int g = 0; g < 8; ++g) a[g] = alphaS[g][p];

    const float* bq = bias + q * 8;
    float* orow = out + (((size_t)b * NFO + (size_t)q * 8) * NH + h) * NW + p;
#pragma unroll
    for (int f = 0; f < 8; ++f) {
        float s = bq[f];
#pragma unroll
        for (int g = 0; g < 8; ++g) s = fmaf(a[g], con[g][f], s);
        orow[(size_t)f * HW] = s;
    }
}

extern "C" void kernel_launch(void* const* d_in, const int* in_sizes, int n_in,
                              void* d_out, int out_size, void* d_ws, size_t ws_size,
                              hipStream_t stream) {
    const float* x      = (const float*)d_in[0];
    const float* weight = (const float*)d_in[1];
    const float* bias   = (const float*)d_in[2];
    float* out = (float*)d_out;

    dynrout_kernel<<<dim3(NB * NH), dim3(512), 0, stream>>>(x, weight, bias, out);
}

// Round 9
// 547.643 us; speedup vs baseline: 1.1566x; 1.1566x over previous
//
#include <hip/hip_runtime.h>

// DynamicRouting: grouped 1x1 conv (G=8, FI=FO=64) + 3-iter sigmoid routing.
// v9: improved split. Evidence: split (v6, 241us GPU) beats every fused variant
// (v5 305, v8 378 -- v8 falsified the pure-occupancy theory: occ 47%, VALU
// still 25%). v6 conv was LDS-issue-bound: 64 ds_read_b32 + addr arith per
// thread vs 512 pk-fma; one LDS pipe/CU serves 4 SIMDs.
// conv v9: 2 px/thread, px pair CONTIGUOUS in LDS -> one ds_read_b64 per
//   channel at constant vaddr (8p) + compile-time imm offset (ch*512): zero
//   addr arith, half the LDS-pipe slots per FLOP, 2x FMA per s_load weight.
//   Tile 64ch x 128px (32 KB), gload_lds width-16 linear staging (v6-proven).
//   acc[16] v2f; stores as dwordx2 (px pair contiguous in con).
// route v9: v8's 512-thread routing block verbatim (proven correct), fed from
//   con workspace: c[8][8]=64 regs (not 128) -> ~6 waves/SIMD, BW-bound.
// Fallback for small ws: v8 fused kernel (passed, 378us).

#define NG 8
#define NFO 64
#define NFI 64
#define NB 32
#define NH 64
#define NW 64
#define HW (NH * NW)   // 4096 pixels per (b, channel) plane

typedef float v2f __attribute__((ext_vector_type(2)));

__device__ __forceinline__ void stage_piece(const float* gsrc, float* ldst) {
    // per-lane global src; wave-uniform LDS dst: lane L writes 16B at ldst+L*16
    __builtin_amdgcn_global_load_lds(
        (const __attribute__((address_space(1))) void*)gsrc,
        (__attribute__((address_space(3))) void*)ldst, 16, 0, 0);
}

// ---------------------------------------------------------------------------
// K1: grouped 1x1 conv.  con[b][g][fo][px] = sum_i w[g][fo][i] * x[b][g*64+i][px]
// Grid = 32 b x 8 g x 32 px-tiles(128) = 8192 WGs, 256 threads.
// Thread = (lane p -> pixels 2p,2p+1 of the tile; wave q -> fo-quarter).
// LDS [64 ch][128 px]; read x per channel as ds_read_b64 (vaddr=8p, imm=ch*512).
// Weights wave-uniform -> s_load. pk-fma with broadcast scalar weight.
// ---------------------------------------------------------------------------
__global__ __launch_bounds__(256) void conv_kernel(
    const float* __restrict__ x, const float* __restrict__ weight,
    float* __restrict__ con)
{
    const int tid = threadIdx.x;
    const int p = tid & 63;
    const int q = __builtin_amdgcn_readfirstlane(tid >> 6);  // fo-quarter

    const int id = blockIdx.x;
    const int t = id & 31;          // px tile (128 px)
    const int g = (id >> 5) & 7;    // group
    const int b = id >> 8;          // batch

    __shared__ __align__(16) float smem[8192];  // [64 ch][128 px] = 32 KB

    // x slab for (b, group g): rows of HW px; our tile at column t*128
    const float* xg = x + ((size_t)b * (NG * NFI) + (size_t)g * NFI) * HW + t * 128;

    // stage 32 KB: one gload_lds inst covers 1 KB = 2 channel rows (512B each).
    // lane L -> ch +(L>>5), px (L&31)*4..+3 (16B contiguous in one ch row).
    const float* gs = xg + (size_t)(p >> 5) * HW + (size_t)(p & 31) * 4;
#pragma unroll
    for (int k = 0; k < 8; ++k) {
        const int chpair = q * 8 + k;                 // wave-uniform
        stage_piece(gs + (size_t)(2 * chpair) * HW, smem + chpair * 256);
    }
    asm volatile("s_waitcnt vmcnt(0)" ::: "memory");
    __builtin_amdgcn_s_barrier();

    v2f acc[16];
#pragma unroll
    for (int f = 0; f < 16; ++f) acc[f] = (v2f){0.f, 0.f};

    const float* wq = weight + ((size_t)g * NFO + (size_t)q * 16) * NFI;

#pragma unroll
    for (int chb = 0; chb < 8; ++chb) {       // 8 channels per block
        v2f xr[8];
#pragma unroll
        for (int j = 0; j < 8; ++j)           // ds_read_b64: vaddr 8p, imm (chb*8+j)*512
            xr[j] = *(const v2f*)&smem[(chb * 8 + j) * 128 + 2 * p];
#pragma unroll
        for (int f = 0; f < 16; ++f) {
            const float* wr = wq + (size_t)f * NFI + chb * 8;   // wave-uniform -> s_load
#pragma unroll
            for (int j = 0; j < 8; ++j) {
                const float w = wr[j];
                acc[f] = __builtin_elementwise_fma((v2f){w, w}, xr[j], acc[f]);
            }
        }
    }

    // con[b][g][fo][px]: px pair contiguous -> dwordx2 stores
    float* crow = con + (((size_t)(b * NG + g) * NFO + (size_t)q * 16)) * HW
                      + t * 128 + 2 * p;
#pragma unroll
    for (int f = 0; f < 16; ++f)
        *(v2f*)(crow + (size_t)f * HW) = acc[f];
}

// ---------------------------------------------------------------------------
// K2: routing. Grid = 32 b x 64 h = 2048 WGs, 512 threads (8 waves).
// Thread = (px p, fo-eighth q): streams c[8][8] from con (coalesced, stride HW)
// then v8's proven routing block. c state = 64 regs -> ~6 waves/SIMD.
// ---------------------------------------------------------------------------
__global__ __launch_bounds__(512) void route_kernel(
    const float* __restrict__ con, const float* __restrict__ bias,
    float* __restrict__ out)
{
    const int tid = threadIdx.x;
    const int p = tid & 63;
    const int q = __builtin_amdgcn_readfirstlane(tid >> 6);  // fo-eighth

    const int id = blockIdx.x;
    const int t = id & 63;          // h
    const int b = id >> 6;

    __shared__ float pbuf[8][8][64];   // per-wave partial beta sums (16 KB)
    __shared__ float alphaS[8][64];
    __shared__ float betaS[8][64];

    float c[8][8];
#pragma unroll
    for (int g = 0; g < 8; ++g) {
        const float* cr = con + (((size_t)(b * NG + g) * NFO + (size_t)q * 8)) * HW
                              + t * 64 + p;
#pragma unroll
        for (int f = 0; f < 8; ++f) c[g][f] = cr[(size_t)f * HW];
    }

    float v[8];

    // iter 0: alpha = sigmoid(0) = 0.5; v0 = 0.5 * sum_g con
#pragma unroll
    for (int f = 0; f < 8; ++f) {
        float s = c[0][f];
#pragma unroll
        for (int g = 1; g < 8; ++g) s += c[g][f];
        v[f] = 0.5f * s;
    }
#pragma unroll
    for (int g = 0; g < 8; ++g) {
        float s = 0.f;
#pragma unroll
        for (int f = 0; f < 8; ++f) s = fmaf(v[f], c[g][f], s);
        pbuf[q][g][p] = s;
    }
    __syncthreads();
    {
        const int gg = tid >> 6, pp = tid & 63;
        float bs = 0.f;
#pragma unroll
        for (int w = 0; w < 8; ++w) bs += pbuf[w][gg][pp];
        betaS[gg][pp] = bs;
        alphaS[gg][pp] = 1.f / (1.f + __expf(-bs));
    }
    __syncthreads();

    // iter 1
    float a[8];
#pragma unroll
    for (int g = 0; g < 8; ++g) a[g] = alphaS[g][p];
#pragma unroll
    for (int f = 0; f < 8; ++f) {
        float s = 0.f;
#pragma unroll
        for (int g = 0; g < 8; ++g) s = fmaf(a[g], c[g][f], s);
        v[f] = s;
    }
#pragma unroll
    for (int g = 0; g < 8; ++g) {
        float s = 0.f;
#pragma unroll
        for (int f = 0; f < 8; ++f) s = fmaf(v[f], c[g][f], s);
        pbuf[q][g][p] = s;
    }
    __syncthreads();
    {
        const int gg = tid >> 6, pp = tid & 63;
        float bs = betaS[gg][pp];
#pragma unroll
        for (int w = 0; w < 8; ++w) bs += pbuf[w][gg][pp];
        alphaS[gg][pp] = 1.f / (1.f + __expf(-bs));
    }
    __syncthreads();

    // iter 2: out = sum_g alpha2*con + bias
#pragma unroll
    for (int g = 0; g < 8; ++g) a[g] = alphaS[g][p];

    const float* bq = bias + q * 8;
    float* orow = out + (((size_t)b * NFO + (size_t)q * 8) * NH + t) * NW + p;
#pragma unroll
    for (int f = 0; f < 8; ++f) {
        float s = bq[f];
#pragma unroll
        for (int g = 0; g < 8; ++g) s = fmaf(a[g], c[g][f], s);
        orow[(size_t)f * HW] = s;
    }
}

// ---------------------------------------------------------------------------
// Fallback: v8 fused kernel verbatim (passed, 378 us) for small ws.
// ---------------------------------------------------------------------------
__global__ __launch_bounds__(512, 2) void dynrout_kernel(
    const float* __restrict__ x, const float* __restrict__ weight,
    const float* __restrict__ bias, float* __restrict__ out)
{
    const int tid = threadIdx.x;
    const int p = tid & 63;
    const int q = __builtin_amdgcn_readfirstlane(tid >> 6);

    const int wg = blockIdx.x;
    const int b = wg >> 6;
    const int h = wg & 63;

    const float* xcol = x + (size_t)b * (NG * NFI) * HW + (size_t)h * NW + p;

    float con[8][8];

#pragma unroll
    for (int g = 0; g < 8; ++g) {
        const float* xg = xcol + (size_t)g * NFI * HW;
        const float* wgb = weight + ((size_t)g * NFO + (size_t)q * 8) * NFI;

        v2f acc[8];
#pragma unroll
        for (int f = 0; f < 8; ++f) acc[f] = (v2f){0.f, 0.f};

#pragma unroll
        for (int sub = 0; sub < 4; ++sub) {
            v2f xr[8];
#pragma unroll
            for (int j = 0; j < 8; ++j) {
                xr[j].x = xg[(size_t)(sub * 16 + 2 * j) * HW];
                xr[j].y = xg[(size_t)(sub * 16 + 2 * j + 1) * HW];
            }
#pragma unroll
            for (int f = 0; f < 8; ++f) {
                const float* wr = wgb + f * NFI + sub * 16;
#pragma unroll
                for (int j = 0; j < 8; ++j) {
                    const v2f wv = *(const v2f*)(wr + 2 * j);
                    acc[f] = __builtin_elementwise_fma(wv, xr[j], acc[f]);
                }
            }
        }
#pragma unroll
        for (int f = 0; f < 8; ++f) con[g][f] = acc[f].x + acc[f].y;

        __builtin_amdgcn_s_barrier();
    }

    __shared__ float pbuf[8][8][64];
    __shared__ float alphaS[8][64];
    __shared__ float betaS[8][64];

    float v[8];
#pragma unroll
    for (int f = 0; f < 8; ++f) {
        float s = con[0][f];
#pragma unroll
        for (int g = 1; g < 8; ++g) s += con[g][f];
        v[f] = 0.5f * s;
    }
#pragma unroll
    for (int g = 0; g < 8; ++g) {
        float s = 0.f;
#pragma unroll
        for (int f = 0; f < 8; ++f) s = fmaf(v[f], con[g][f], s);
        pbuf[q][g][p] = s;
    }
    __syncthreads();
    {
        const int gg = tid >> 6, pp = tid & 63;
        float bs = 0.f;
#pragma unroll
        for (int w = 0; w < 8; ++w) bs += pbuf[w][gg][pp];
        betaS[gg][pp] = bs;
        alphaS[gg][pp] = 1.f / (1.f + __expf(-bs));
    }
    __syncthreads();

    float a[8];
#pragma unroll
    for (int g = 0; g < 8; ++g) a[g] = alphaS[g][p];
#pragma unroll
    for (int f = 0; f < 8; ++f) {
        float s = 0.f;
#pragma unroll
        for (int g = 0; g < 8; ++g) s = fmaf(a[g], con[g][f], s);
        v[f] = s;
    }
#pragma unroll
    for (int g = 0; g < 8; ++g) {
        float s = 0.f;
#pragma unroll
        for (int f = 0; f < 8; ++f) s = fmaf(v[f], con[g][f], s);
        pbuf[q][g][p] = s;
    }
    __syncthreads();
    {
        const int gg = tid >> 6, pp = tid & 63;
        float bs = betaS[gg][pp];
#pragma unroll
        for (int w = 0; w < 8; ++w) bs += pbuf[w][gg][pp];
        alphaS[gg][pp] = 1.f / (1.f + __expf(-bs));
    }
    __syncthreads();

#pragma unroll
    for (int g = 0; g < 8; ++g) a[g] = alphaS[g][p];

    const float* bq = bias + q * 8;
    float* orow = out + (((size_t)b * NFO + (size_t)q * 8) * NH + h) * NW + p;
#pragma unroll
    for (int f = 0; f < 8; ++f) {
        float s = bq[f];
#pragma unroll
        for (int g = 0; g < 8; ++g) s = fmaf(a[g], con[g][f], s);
        orow[(size_t)f * HW] = s;
    }
}

extern "C" void kernel_launch(void* const* d_in, const int* in_sizes, int n_in,
                              void* d_out, int out_size, void* d_ws, size_t ws_size,
                              hipStream_t stream) {
    const float* x      = (const float*)d_in[0];
    const float* weight = (const float*)d_in[1];
    const float* bias   = (const float*)d_in[2];
    float* out = (float*)d_out;

    const size_t need = (size_t)NB * NG * NFO * HW * sizeof(float);  // 268 MB
    if (d_ws != nullptr && ws_size >= need) {
        float* con = (float*)d_ws;
        conv_kernel<<<dim3(NB * NG * 32), dim3(256), 0, stream>>>(x, weight, con);
        route_kernel<<<dim3(NB * 64), dim3(512), 0, stream>>>(con, bias, out);
    } else {
        dynrout_kernel<<<dim3(NB * NH), dim3(512), 0, stream>>>(x, weight, bias, out);
    }
}